// Round 6
// baseline (124.600 us; speedup 1.0000x reference)
//
#include <hip/hip_runtime.h>

#define BLOCK 256
#define LOG_2PI_F 1.8378770664093453f

// ws layout (float offsets):
//   0..7   : stats: [2] ld_sum0 [3] ld_sum1 [4] cnt0 [5] cnt1
//   8..9   : Bc[2] = sum_d b[c,d]   (atomic accum, zeroed by memset)
//   16     : p_tab [2*D]   (= 0.5*exp(-2*lsd))
//   16+2D  : q_tab [2*D]   (= 2*p*mu)
//   16+4D  : tgtf  [N]     (= (float)(target[n]!=0))
//   PART0  : partials [2(z)][gyR][gx][2][1024]  (plane 0 = sumAll, 1 = sumC1)

// one block: build tgtf + counts + logdet sums
__global__ __launch_bounds__(1024) void k_prep(
    const int*   __restrict__ target,
    const float* __restrict__ logdet,
    float* __restrict__ tgtf,
    float* __restrict__ stats,
    int N)
{
    const int tid = threadIdx.x;
    float ldA = 0.f, ld1 = 0.f;
    int   c1  = 0;
    if ((N & 4095) == 0) {
        const int4*   t4 = reinterpret_cast<const int4*>(target);
        const float4* l4 = reinterpret_cast<const float4*>(logdet);
        float4*       g4 = reinterpret_cast<float4*>(tgtf);
        const int n4 = N >> 2;
        for (int i = tid; i < n4; i += 1024) {
            const int4   t = t4[i];
            const float4 v = l4[i];
            float4 w;
            w.x = t.x ? 1.f : 0.f;
            w.y = t.y ? 1.f : 0.f;
            w.z = t.z ? 1.f : 0.f;
            w.w = t.w ? 1.f : 0.f;
            g4[i] = w;
            ldA += v.x + v.y + v.z + v.w;
            ld1 += w.x * v.x + w.y * v.y + w.z * v.z + w.w * v.w;
            c1  += (t.x ? 1 : 0) + (t.y ? 1 : 0) + (t.z ? 1 : 0) + (t.w ? 1 : 0);
        }
    } else {
        for (int n = tid; n < N; n += 1024) {
            const int   t = target[n];
            const float v = logdet[n];
            const float w = t ? 1.f : 0.f;
            tgtf[n] = w;
            ldA += v; ld1 += w * v; c1 += t ? 1 : 0;
        }
    }
    __shared__ float sB[1024], sC[1024];
    __shared__ int   sI[1024];
    sB[tid] = ldA; sC[tid] = ld1; sI[tid] = c1;
    __syncthreads();
    for (int off = 512; off > 0; off >>= 1) {
        if (tid < off) {
            sB[tid] += sB[tid + off];
            sC[tid] += sC[tid + off];
            sI[tid] += sI[tid + off];
        }
        __syncthreads();
    }
    if (tid == 0) {
        stats[2] = sB[0] - sC[0];          // ld_sum0
        stats[3] = sC[0];                  // ld_sum1
        stats[4] = (float)(N - sI[0]);     // cnt0
        stats[5] = (float)sI[0];           // cnt1
    }
}

// streaming column partial sums: thread <-> one float4 column, small row slice
__global__ __launch_bounds__(BLOCK) void k_colsum(
    const float* __restrict__ mean,
    const float* __restrict__ log_sd,
    const float* __restrict__ tgtf,
    float* __restrict__ partials,
    int N, int D4, int rowsPerBlk, int gyR)
{
    const int c4 = blockIdx.x * BLOCK + threadIdx.x;   // float4 column
    const bool colOK = (c4 < D4);
    const int rowBase = blockIdx.y * rowsPerBlk;
    int rEnd = rowsPerBlk;
    if (rowBase + rEnd > N) rEnd = N - rowBase;
    if (rEnd < 0) rEnd = 0;

    const float4* src4 =
        reinterpret_cast<const float4*>(blockIdx.z == 0 ? mean : log_sd);
    const float4* p  = src4 + (size_t)rowBase * D4 + (colOK ? c4 : 0);
    const float*  wp = tgtf + rowBase;

    float4 sA = make_float4(0.f, 0.f, 0.f, 0.f);
    float4 s1 = make_float4(0.f, 0.f, 0.f, 0.f);

    int r = 0;
    for (; r + 4 <= rEnd; r += 4) {
        const float4 w4 = *reinterpret_cast<const float4*>(wp + r);
        const float4 d0 = p[(size_t)(r + 0) * D4];
        const float4 d1 = p[(size_t)(r + 1) * D4];
        const float4 d2 = p[(size_t)(r + 2) * D4];
        const float4 d3 = p[(size_t)(r + 3) * D4];
        sA.x += d0.x; sA.y += d0.y; sA.z += d0.z; sA.w += d0.w;
        s1.x = fmaf(d0.x, w4.x, s1.x); s1.y = fmaf(d0.y, w4.x, s1.y);
        s1.z = fmaf(d0.z, w4.x, s1.z); s1.w = fmaf(d0.w, w4.x, s1.w);
        sA.x += d1.x; sA.y += d1.y; sA.z += d1.z; sA.w += d1.w;
        s1.x = fmaf(d1.x, w4.y, s1.x); s1.y = fmaf(d1.y, w4.y, s1.y);
        s1.z = fmaf(d1.z, w4.y, s1.z); s1.w = fmaf(d1.w, w4.y, s1.w);
        sA.x += d2.x; sA.y += d2.y; sA.z += d2.z; sA.w += d2.w;
        s1.x = fmaf(d2.x, w4.z, s1.x); s1.y = fmaf(d2.y, w4.z, s1.y);
        s1.z = fmaf(d2.z, w4.z, s1.z); s1.w = fmaf(d2.w, w4.z, s1.w);
        sA.x += d3.x; sA.y += d3.y; sA.z += d3.z; sA.w += d3.w;
        s1.x = fmaf(d3.x, w4.w, s1.x); s1.y = fmaf(d3.y, w4.w, s1.y);
        s1.z = fmaf(d3.z, w4.w, s1.z); s1.w = fmaf(d3.w, w4.w, s1.w);
    }
    for (; r < rEnd; ++r) {
        const float4 d = p[(size_t)r * D4];
        const float  w = wp[r];
        sA.x += d.x; sA.y += d.y; sA.z += d.z; sA.w += d.w;
        s1.x = fmaf(d.x, w, s1.x);
        s1.y = fmaf(d.y, w, s1.y);
        s1.z = fmaf(d.z, w, s1.z);
        s1.w = fmaf(d.w, w, s1.w);
    }

    if (colOK) {
        float* pt = partials +
            (((size_t)blockIdx.z * gyR + blockIdx.y) * gridDim.x + blockIdx.x) * 2048;
        reinterpret_cast<float4*>(pt)[threadIdx.x]        = sA;   // sumAll
        reinterpret_cast<float4*>(pt + 1024)[threadIdx.x] = s1;   // sumC1
    }
}

// reduce partials over gyR (4 threads per output), finalize params + tables + Bc
__global__ __launch_bounds__(BLOCK) void k_reduce_finalize(
    const float* __restrict__ partials,
    float* __restrict__ ws,
    float* __restrict__ out,
    int D, int gx, int gyR)
{
    const int sub  = threadIdx.x & 3;                       // quarter of gyR
    const int slot = threadIdx.x >> 2;                      // 0..63
    const int oidx = blockIdx.x * 64 + slot;                // [0, 2*D)
    const bool ok  = (oidx < 2 * D);
    const int cls = ok ? (oidx / D) : 0;
    const int col = ok ? (oidx - cls * D) : 0;
    const int bx  = col >> 10;
    const int cc  = col & 1023;

    const size_t strideY = (size_t)gx * 2048;
    const float* pm = partials + (size_t)bx * 2048 + cc;    // z=0 (mean)
    const float* pl = pm + (size_t)gyR * strideY;           // z=1 (log_sd)

    float mA = 0.f, m1 = 0.f, lA = 0.f, l1 = 0.f;
    const int per = gyR >> 2;
    for (int j = 0; j < per; ++j) {
        const size_t o = (size_t)(sub * per + j) * strideY;
        mA += pm[o]; m1 += pm[o + 1024];
        lA += pl[o]; l1 += pl[o + 1024];
    }
    // combine the 4 subs (consecutive lanes) in-register
    #pragma unroll
    for (int s = 1; s <= 2; s <<= 1) {
        mA += __shfl_xor(mA, s);
        m1 += __shfl_xor(m1, s);
        lA += __shfl_xor(lA, s);
        l1 += __shfl_xor(l1, s);
    }

    float b = 0.f;
    if (ok) {
        const float cnt = ws[4 + cls];
        const float m = (cls ? m1 : (mA - m1)) / cnt;
        const float l = (cls ? l1 : (lA - l1)) / cnt;
        const float pv = 0.5f * expf(-2.f * l);
        b = -0.5f * LOG_2PI_F - l - pv * m * m;
        if (sub == 0) {
            out[1 + oidx]         = m;   // mus
            out[1 + 2 * D + oidx] = l;   // lsds
            float* p_tab = ws + 16;
            float* q_tab = p_tab + 2 * D;
            p_tab[oidx] = pv;
            q_tab[oidx] = 2.f * pv * m;
        }
    }

    __shared__ float sB[64];
    __shared__ int   sCls[64];
    if (sub == 0) { sB[slot] = ok ? b : 0.f; sCls[slot] = cls; }
    __syncthreads();
    if (threadIdx.x == 0) {
        float b0 = 0.f, b1 = 0.f;
        for (int j = 0; j < 64; ++j) {
            if (sCls[j]) b1 += sB[j]; else b0 += sB[j];
        }
        atomicAdd(&ws[8], b0);
        atomicAdd(&ws[9], b1);
    }
}

__global__ __launch_bounds__(BLOCK) void k_logp(
    const float* __restrict__ z,
    const int*   __restrict__ target,
    const float* __restrict__ ws,
    float* __restrict__ logp_out,
    int N, int D)
{
    const int wave = threadIdx.x >> 6;
    const int lane = threadIdx.x & 63;
    const int n    = blockIdx.x * 4 + wave;
    const int D4   = D >> 2;
    if (n >= N) return;

    const int t = __builtin_amdgcn_readfirstlane(target[n]);
    const float Bc = ws[8 + t];
    const float4* z4 = reinterpret_cast<const float4*>(z) + (size_t)n * D4;
    const float4* p4 = reinterpret_cast<const float4*>(ws + 16) + (size_t)t * D4;
    const float4* q4 = p4 + 2 * D4;

    float acc = 0.f;
    int i = lane;
    for (; i + 64 < D4; i += 128) {
        const float4 zz0 = z4[i];      const float4 zz1 = z4[i + 64];
        const float4 pp0 = p4[i];      const float4 pp1 = p4[i + 64];
        const float4 qq0 = q4[i];      const float4 qq1 = q4[i + 64];
        acc += zz0.x * (qq0.x - pp0.x * zz0.x);
        acc += zz0.y * (qq0.y - pp0.y * zz0.y);
        acc += zz0.z * (qq0.z - pp0.z * zz0.z);
        acc += zz0.w * (qq0.w - pp0.w * zz0.w);
        acc += zz1.x * (qq1.x - pp1.x * zz1.x);
        acc += zz1.y * (qq1.y - pp1.y * zz1.y);
        acc += zz1.z * (qq1.z - pp1.z * zz1.z);
        acc += zz1.w * (qq1.w - pp1.w * zz1.w);
    }
    for (; i < D4; i += 64) {
        const float4 zz = z4[i];
        const float4 pp = p4[i];
        const float4 qq = q4[i];
        acc += zz.x * (qq.x - pp.x * zz.x);
        acc += zz.y * (qq.y - pp.y * zz.y);
        acc += zz.z * (qq.z - pp.z * zz.z);
        acc += zz.w * (qq.w - pp.w * zz.w);
    }

    #pragma unroll
    for (int m = 32; m >= 1; m >>= 1) acc += __shfl_xor(acc, m);
    if (lane == 0) logp_out[n] = acc + Bc;
}

__global__ __launch_bounds__(1024) void k_finalize2(
    const float* __restrict__ logp,
    const int*   __restrict__ target,
    const float* __restrict__ stats,
    float* __restrict__ out,
    int N, int out_off)
{
    const int tid = threadIdx.x;
    float cA = 0.f, c1 = 0.f;
    if ((N & 4095) == 0) {
        const float4* lp4 = reinterpret_cast<const float4*>(logp);
        const int4*   t4  = reinterpret_cast<const int4*>(target);
        for (int i = tid; i < (N >> 2); i += 1024) {
            const float4 v = lp4[i];
            const int4   t = t4[i];
            cA += v.x + v.y + v.z + v.w;
            if (t.x) c1 += v.x;
            if (t.y) c1 += v.y;
            if (t.z) c1 += v.z;
            if (t.w) c1 += v.w;
        }
    } else {
        for (int i = tid; i < N; i += 1024) {
            const float v = logp[i];
            cA += v;
            if (target[i]) c1 += v;
        }
    }
    __shared__ float s0[1024];
    __shared__ float s1[1024];
    s0[tid] = cA; s1[tid] = c1;
    __syncthreads();
    for (int off = 512; off > 0; off >>= 1) {
        if (tid < off) {
            s0[tid] += s0[tid + off];
            s1[tid] += s1[tid + off];
        }
        __syncthreads();
    }
    if (tid == 0) {
        const float lp0 = (s0[0] - s1[0]) / stats[4];
        const float lp1 = s1[0] / stats[5];
        const float ld0 = stats[2] / stats[4];
        const float ld1 = stats[3] / stats[5];
        out[out_off]     = lp0;            // log_p_total[0]
        out[out_off + 1] = lp1;            // log_p_total[1]
        out[0] = 0.5f * ((lp0 + ld0) + (lp1 + ld1));  // prior_logprob
    }
}

extern "C" void kernel_launch(void* const* d_in, const int* in_sizes, int n_in,
                              void* d_out, int out_size, void* d_ws, size_t ws_size,
                              hipStream_t stream)
{
    const float* z      = (const float*)d_in[0];
    const float* mean   = (const float*)d_in[1];
    const float* log_sd = (const float*)d_in[2];
    const float* logdet = (const float*)d_in[3];
    const int*   target = (const int*)d_in[4];
    float* out = (float*)d_out;
    float* ws  = (float*)d_ws;

    const int N = in_sizes[3];            // 8192
    const int D = in_sizes[0] / N;        // 3072
    const int D4 = D >> 2;                // 768
    const int gx = (D4 + BLOCK - 1) / BLOCK;   // 3

    // regions
    float* tgtf = ws + 16 + 4 * D;
    size_t part0 = (size_t)(16 + 4 * D + N);
    part0 = (part0 + 255) & ~(size_t)255;

    // pick gyR (power of 2, >=4) so partials fit in ws
    int gyR = 512;
    while (gyR > 4 &&
           (part0 + (size_t)2 * gyR * gx * 2048) * sizeof(float) > ws_size)
        gyR >>= 1;
    const int rowsPerBlk = (N + gyR - 1) / gyR;

    float* partials = ws + part0;

    // zero Bc accumulators (+ stats header)
    hipMemsetAsync(d_ws, 0, 16 * sizeof(float), stream);

    // prep: tgtf + counts + logdet sums
    k_prep<<<1, 1024, 0, stream>>>(target, logdet, tgtf, ws, N);

    // pass 1: streaming per-class column partial sums (TLP-heavy grid)
    dim3 g1(gx, gyR, 2);
    k_colsum<<<g1, BLOCK, 0, stream>>>(mean, log_sd, tgtf, partials,
                                       N, D4, rowsPerBlk, gyR);

    // reduce partials + finalize class params + build p/q tables + Bc
    const int nred = (2 * D + 63) / 64;
    k_reduce_finalize<<<nred, BLOCK, 0, stream>>>(partials, ws, out, D, gx, gyR);

    // pass 2: per-sample logp (one wave per row)
    float* logp_out = out + 1 + 4 * D;
    k_logp<<<(N + 3) / 4, BLOCK, 0, stream>>>(z, target, ws, logp_out, N, D);

    // epilogue: class logp means + prior
    k_finalize2<<<1, 1024, 0, stream>>>(logp_out, target, ws, out,
                                        N, 1 + 4 * D + N);
}

// Round 7
// 98.208 us; speedup vs baseline: 1.2687x; 1.2687x over previous
//
#include <hip/hip_runtime.h>

#define BLOCK 256
#define LOG_2PI_F 1.8378770664093453f

// ws layout (float offsets):
//   0..7   : stats: [2] ld_sum0 [3] ld_sum1 [4] cnt0 [5] cnt1
//   16     : p_tab [2*D]   (= 0.5*exp(-2*lsd))
//   16+2D  : q_tab [2*D]   (= 2*p*mu)
//   PART0  : partials [2(z)][gyR][2][Dp]   (plane 0 = sumAll, 1 = sumC1), Dp = D
//
// out layout: [0] prior | [1,1+2D) mus | [1+2D,1+4D) lsds |
//             [1+4D,1+4D+N) logp | [1+4D+N, +2) log_p_total

__device__ __forceinline__ void acc4(float4& s, const float4 d) {
    s.x += d.x; s.y += d.y; s.z += d.z; s.w += d.w;
}
__device__ __forceinline__ void fma4(float4& s, const float4 d, const float w) {
    s.x = fmaf(d.x, w, s.x); s.y = fmaf(d.y, w, s.y);
    s.z = fmaf(d.z, w, s.z); s.w = fmaf(d.w, w, s.w);
}

// shared stats helper: counts + per-class logdet sums (run by one block)
__device__ void do_stats(const int* __restrict__ target,
                         const float* __restrict__ logdet,
                         float* __restrict__ stats, int N)
{
    const int tid = threadIdx.x;
    float ldA = 0.f, ld1 = 0.f;
    int   c1  = 0;
    if ((N & 3) == 0) {
        const int4*   t4 = reinterpret_cast<const int4*>(target);
        const float4* l4 = reinterpret_cast<const float4*>(logdet);
        for (int i = tid; i < (N >> 2); i += BLOCK) {
            const int4   t = t4[i];
            const float4 v = l4[i];
            ldA += v.x + v.y + v.z + v.w;
            if (t.x) { c1++; ld1 += v.x; }
            if (t.y) { c1++; ld1 += v.y; }
            if (t.z) { c1++; ld1 += v.z; }
            if (t.w) { c1++; ld1 += v.w; }
        }
    } else {
        for (int n = tid; n < N; n += BLOCK) {
            const float v = logdet[n];
            ldA += v;
            if (target[n]) { c1++; ld1 += v; }
        }
    }
    __shared__ float sB[BLOCK], sC[BLOCK];
    __shared__ int   sI[BLOCK];
    sB[tid] = ldA; sC[tid] = ld1; sI[tid] = c1;
    __syncthreads();
    for (int off = BLOCK / 2; off > 0; off >>= 1) {
        if (tid < off) {
            sB[tid] += sB[tid + off];
            sC[tid] += sC[tid + off];
            sI[tid] += sI[tid + off];
        }
        __syncthreads();
    }
    if (tid == 0) {
        stats[2] = sB[0] - sC[0];          // ld_sum0
        stats[3] = sC[0];                  // ld_sum1
        stats[4] = (float)(N - sI[0]);     // cnt0
        stats[5] = (float)sI[0];           // cnt1
    }
}

// fast path (D == 3072): block streams full row width contiguously
__global__ __launch_bounds__(BLOCK, 4) void k_colsum3(
    const float* __restrict__ mean,
    const float* __restrict__ log_sd,
    const int*   __restrict__ target,
    const float* __restrict__ logdet,
    float* __restrict__ partials,
    float* __restrict__ stats,
    int N, int rowsPerBlk, int gyR)
{
    const int tid = threadIdx.x;
    const int by  = blockIdx.x;
    const int z   = blockIdx.y;
    const int D4  = 768;                        // 3072 / 4
    const int rowBase = by * rowsPerBlk;
    int rEnd = rowsPerBlk;
    if (rowBase + rEnd > N) rEnd = N - rowBase;
    if (rEnd < 0) rEnd = 0;

    const float4* src4 =
        reinterpret_cast<const float4*>(z == 0 ? mean : log_sd);
    const float4* p   = src4 + (size_t)rowBase * D4 + tid;
    const int*    tgt = target + rowBase;

    float4 sA0 = make_float4(0.f,0.f,0.f,0.f);
    float4 sA1 = make_float4(0.f,0.f,0.f,0.f);
    float4 sA2 = make_float4(0.f,0.f,0.f,0.f);
    float4 s10 = make_float4(0.f,0.f,0.f,0.f);
    float4 s11 = make_float4(0.f,0.f,0.f,0.f);
    float4 s12 = make_float4(0.f,0.f,0.f,0.f);

    int r = 0;
    for (; r + 2 <= rEnd; r += 2) {
        const float wA = tgt[r]     ? 1.f : 0.f;   // block-uniform scalar load
        const float wB = tgt[r + 1] ? 1.f : 0.f;
        const float4* ra = p + (size_t)r * D4;
        const float4* rb = ra + D4;
        const float4 a0 = ra[0];
        const float4 a1 = ra[256];
        const float4 a2 = ra[512];
        const float4 b0 = rb[0];
        const float4 b1 = rb[256];
        const float4 b2 = rb[512];
        acc4(sA0, a0); fma4(s10, a0, wA);
        acc4(sA1, a1); fma4(s11, a1, wA);
        acc4(sA2, a2); fma4(s12, a2, wA);
        acc4(sA0, b0); fma4(s10, b0, wB);
        acc4(sA1, b1); fma4(s11, b1, wB);
        acc4(sA2, b2); fma4(s12, b2, wB);
    }
    for (; r < rEnd; ++r) {
        const float w = tgt[r] ? 1.f : 0.f;
        const float4* ra = p + (size_t)r * D4;
        const float4 a0 = ra[0];
        const float4 a1 = ra[256];
        const float4 a2 = ra[512];
        acc4(sA0, a0); fma4(s10, a0, w);
        acc4(sA1, a1); fma4(s11, a1, w);
        acc4(sA2, a2); fma4(s12, a2, w);
    }

    // coalesced partial stores: [plane0|plane1] x 3072 floats
    float* base = partials + ((size_t)z * gyR + by) * (2 * 3072);
    float4* pl0 = reinterpret_cast<float4*>(base);
    float4* pl1 = reinterpret_cast<float4*>(base + 3072);
    pl0[tid]       = sA0; pl0[tid + 256] = sA1; pl0[tid + 512] = sA2;
    pl1[tid]       = s10; pl1[tid + 256] = s11; pl1[tid + 512] = s12;

    if (by == 0 && z == 0) do_stats(target, logdet, stats, N);
}

// generic fallback (any D): column-group blocks (non-contiguous, correct)
__global__ __launch_bounds__(BLOCK, 4) void k_colsum_gen(
    const float* __restrict__ mean,
    const float* __restrict__ log_sd,
    const int*   __restrict__ target,
    const float* __restrict__ logdet,
    float* __restrict__ partials,
    float* __restrict__ stats,
    int N, int D4, int Dp, int rowsPerBlk, int gyR)
{
    const int c4 = blockIdx.x * BLOCK + threadIdx.x;
    const bool colOK = (c4 < D4);
    const int rowBase = blockIdx.y * rowsPerBlk;
    int rEnd = rowsPerBlk;
    if (rowBase + rEnd > N) rEnd = N - rowBase;
    if (rEnd < 0) rEnd = 0;

    const float4* src4 =
        reinterpret_cast<const float4*>(blockIdx.z == 0 ? mean : log_sd);
    const float4* p   = src4 + (size_t)rowBase * D4 + (colOK ? c4 : 0);
    const int*    tgt = target + rowBase;

    float4 sA = make_float4(0.f,0.f,0.f,0.f);
    float4 s1 = make_float4(0.f,0.f,0.f,0.f);
    for (int r = 0; r < rEnd; ++r) {
        const float w = tgt[r] ? 1.f : 0.f;
        const float4 d = p[(size_t)r * D4];
        acc4(sA, d); fma4(s1, d, w);
    }

    if (colOK) {
        float* base = partials +
            ((size_t)blockIdx.z * gyR + blockIdx.y) * (2 * (size_t)Dp);
        reinterpret_cast<float4*>(base)[c4]      = sA;
        reinterpret_cast<float4*>(base + Dp)[c4] = s1;
    }
    if (blockIdx.x == 0 && blockIdx.y == 0 && blockIdx.z == 0)
        do_stats(target, logdet, stats, N);
}

// reduce partials over gyR (8 threads per output), finalize params + tables
__global__ __launch_bounds__(BLOCK) void k_reduce_finalize(
    const float* __restrict__ partials,
    float* __restrict__ ws,
    float* __restrict__ out,
    int D, int Dp, int gyR)
{
    const int sub  = threadIdx.x & 7;
    const int slot = threadIdx.x >> 3;                 // 0..31
    const int oidx = blockIdx.x * 32 + slot;           // [0, 2*D)
    const bool ok  = (oidx < 2 * D);
    const int cls = ok ? (oidx / D) : 0;
    const int col = ok ? (oidx - cls * D) : 0;

    const size_t strideBY = 2 * (size_t)Dp;
    const size_t zoff     = (size_t)gyR * strideBY;
    const int per = gyR >> 3;

    float mA = 0.f, m1 = 0.f, lA = 0.f, l1 = 0.f;
    for (int j = 0; j < per; ++j) {
        const size_t base = (size_t)(sub * per + j) * strideBY + col;
        mA += partials[base];
        m1 += partials[base + Dp];
        lA += partials[zoff + base];
        l1 += partials[zoff + base + Dp];
    }
    #pragma unroll
    for (int s = 1; s <= 4; s <<= 1) {
        mA += __shfl_xor(mA, s);
        m1 += __shfl_xor(m1, s);
        lA += __shfl_xor(lA, s);
        l1 += __shfl_xor(l1, s);
    }

    if (ok && sub == 0) {
        const float cnt = ws[4 + cls];
        const float m = (cls ? m1 : (mA - m1)) / cnt;
        const float l = (cls ? l1 : (lA - l1)) / cnt;
        out[1 + oidx]         = m;   // mus
        out[1 + 2 * D + oidx] = l;   // lsds
        float* p_tab = ws + 16;
        float* q_tab = p_tab + 2 * D;
        const float pv = 0.5f * expf(-2.f * l);
        p_tab[oidx] = pv;
        q_tab[oidx] = 2.f * pv * m;
    }
}

__global__ __launch_bounds__(BLOCK) void k_logp(
    const float* __restrict__ z,
    const int*   __restrict__ target,
    const float* __restrict__ ws,
    float* __restrict__ logp_out,
    int N, int D)
{
    const int wave = threadIdx.x >> 6;
    const int lane = threadIdx.x & 63;
    const int n    = blockIdx.x * 4 + wave;
    const int D4   = D >> 2;
    if (n >= N) return;

    const int t = __builtin_amdgcn_readfirstlane(target[n]);
    const float4* z4 = reinterpret_cast<const float4*>(z) + (size_t)n * D4;
    const float4* p4 = reinterpret_cast<const float4*>(ws + 16) + (size_t)t * D4;
    const float4* q4 = p4 + 2 * D4;

    float acc = 0.f;
    int i = lane;
    for (; i + 64 < D4; i += 128) {
        const float4 zz0 = z4[i];      const float4 zz1 = z4[i + 64];
        const float4 pp0 = p4[i];      const float4 pp1 = p4[i + 64];
        const float4 qq0 = q4[i];      const float4 qq1 = q4[i + 64];
        acc += zz0.x * (qq0.x - pp0.x * zz0.x);
        acc += zz0.y * (qq0.y - pp0.y * zz0.y);
        acc += zz0.z * (qq0.z - pp0.z * zz0.z);
        acc += zz0.w * (qq0.w - pp0.w * zz0.w);
        acc += zz1.x * (qq1.x - pp1.x * zz1.x);
        acc += zz1.y * (qq1.y - pp1.y * zz1.y);
        acc += zz1.z * (qq1.z - pp1.z * zz1.z);
        acc += zz1.w * (qq1.w - pp1.w * zz1.w);
    }
    for (; i < D4; i += 64) {
        const float4 zz = z4[i];
        const float4 pp = p4[i];
        const float4 qq = q4[i];
        acc += zz.x * (qq.x - pp.x * zz.x);
        acc += zz.y * (qq.y - pp.y * zz.y);
        acc += zz.z * (qq.z - pp.z * zz.z);
        acc += zz.w * (qq.w - pp.w * zz.w);
    }

    #pragma unroll
    for (int m = 32; m >= 1; m >>= 1) acc += __shfl_xor(acc, m);
    if (lane == 0) logp_out[n] = acc;        // Bc added in k_finalize2
}

// epilogue: per-class Bc from mus/lsds, patch logp, class means, prior
__global__ __launch_bounds__(1024) void k_finalize2(
    const int*   __restrict__ target,
    const float* __restrict__ stats,
    float* __restrict__ out,
    int N, int D, int out_off)
{
    const int tid = threadIdx.x;
    const float* mus  = out + 1;
    const float* lsds = out + 1 + 2 * D;
    float* logp = out + 1 + 4 * D;

    // phase 1: Bc[cls] = sum_d ( -0.5*log2pi - l - 0.5*exp(-2l)*m^2 )
    float b0 = 0.f, b1 = 0.f;
    for (int idx = tid; idx < 2 * D; idx += 1024) {
        const float m = mus[idx];
        const float l = lsds[idx];
        const float b = -0.5f * LOG_2PI_F - l - 0.5f * expf(-2.f * l) * m * m;
        if (idx < D) b0 += b; else b1 += b;
    }
    __shared__ float s0[1024];
    __shared__ float s1[1024];
    s0[tid] = b0; s1[tid] = b1;
    __syncthreads();
    for (int off = 512; off > 0; off >>= 1) {
        if (tid < off) {
            s0[tid] += s0[tid + off];
            s1[tid] += s1[tid + off];
        }
        __syncthreads();
    }
    const float B0 = s0[0];
    const float B1 = s1[0];
    __syncthreads();

    // phase 2: patch logp with Bc, accumulate per-class sums
    float cA = 0.f, c1 = 0.f;
    for (int i = tid; i < N; i += 1024) {
        const int   t = target[i];
        const float v = logp[i] + (t ? B1 : B0);
        logp[i] = v;
        cA += v;
        if (t) c1 += v;
    }
    s0[tid] = cA; s1[tid] = c1;
    __syncthreads();
    for (int off = 512; off > 0; off >>= 1) {
        if (tid < off) {
            s0[tid] += s0[tid + off];
            s1[tid] += s1[tid + off];
        }
        __syncthreads();
    }
    if (tid == 0) {
        const float lp0 = (s0[0] - s1[0]) / stats[4];
        const float lp1 = s1[0] / stats[5];
        const float ld0 = stats[2] / stats[4];
        const float ld1 = stats[3] / stats[5];
        out[out_off]     = lp0;            // log_p_total[0]
        out[out_off + 1] = lp1;            // log_p_total[1]
        out[0] = 0.5f * ((lp0 + ld0) + (lp1 + ld1));  // prior_logprob
    }
}

extern "C" void kernel_launch(void* const* d_in, const int* in_sizes, int n_in,
                              void* d_out, int out_size, void* d_ws, size_t ws_size,
                              hipStream_t stream)
{
    const float* z      = (const float*)d_in[0];
    const float* mean   = (const float*)d_in[1];
    const float* log_sd = (const float*)d_in[2];
    const float* logdet = (const float*)d_in[3];
    const int*   target = (const int*)d_in[4];
    float* out = (float*)d_out;
    float* ws  = (float*)d_ws;

    const int N  = in_sizes[3];            // 8192
    const int D  = in_sizes[0] / N;        // 3072
    const int D4 = D >> 2;                 // 768
    const int Dp = D4 * 4;                 // padded plane width (== D here)

    size_t part0 = (size_t)(16 + 4 * D);
    part0 = (part0 + 255) & ~(size_t)255;

    // pick gyR (power of 2, >= 8) so partials fit in ws
    int gyR = 512;
    while (gyR > 8 &&
           (part0 + (size_t)2 * gyR * 2 * Dp) * sizeof(float) > ws_size)
        gyR >>= 1;
    const int rowsPerBlk = (N + gyR - 1) / gyR;

    float* partials = ws + part0;

    // pass 1: streaming per-class column partial sums (+ stats in block 0)
    if (D4 == 768) {
        dim3 g1(gyR, 2);
        k_colsum3<<<g1, BLOCK, 0, stream>>>(mean, log_sd, target, logdet,
                                            partials, ws, N, rowsPerBlk, gyR);
    } else {
        dim3 g1((D4 + BLOCK - 1) / BLOCK, gyR, 2);
        k_colsum_gen<<<g1, BLOCK, 0, stream>>>(mean, log_sd, target, logdet,
                                               partials, ws, N, D4, Dp,
                                               rowsPerBlk, gyR);
    }

    // reduce partials + finalize class params + build p/q tables
    const int nred = (2 * D + 31) / 32;
    k_reduce_finalize<<<nred, BLOCK, 0, stream>>>(partials, ws, out, D, Dp, gyR);

    // pass 2: per-sample logp (one wave per row)
    float* logp_out = out + 1 + 4 * D;
    k_logp<<<(N + 3) / 4, BLOCK, 0, stream>>>(z, target, ws, logp_out, N, D);

    // epilogue: Bc + patch logp + class means + prior
    k_finalize2<<<1, 1024, 0, stream>>>(target, ws, out, N, D, 1 + 4 * D + N);
}